// Round 4
// baseline (10450.407 us; speedup 1.0000x reference)
//
#include <hip/hip_runtime.h>
#include <hip/hip_bf16.h>

#define BB 64
#define TT 2048
#define II 128
#define HH 256
#define GG 768   // 3*H

typedef _Float16 h2 __attribute__((ext_vector_type(2)));
typedef _Float16 half8 __attribute__((ext_vector_type(8)));
typedef float f32x4 __attribute__((ext_vector_type(4)));
union U32H2 { unsigned int u; h2 h; };

static __device__ __forceinline__ float fdot2f(unsigned int w, h2 hv, float acc){
#if __has_builtin(__builtin_amdgcn_fdot2)
    U32H2 c; c.u = w;
    return __builtin_amdgcn_fdot2(c.h, hv, acc, false);
#else
    U32H2 c; c.u = w;
    return acc + (float)c.h.x * (float)hv.x + (float)c.h.y * (float)hv.y;
#endif
}

// ---------------------------------------------------------------------------
// Phase 0a: W_hh [768][256] f32 -> packed f16 pairs, transposed:
// Wt[kk][g] = pack(W_hh[g][2kk], W_hh[g][2kk+1]), kk in [0,128), g in [0,768)
// ---------------------------------------------------------------------------
__global__ void conv_whh(const float* __restrict__ Whh, unsigned int* __restrict__ Wt){
    int idx = blockIdx.x * 256 + threadIdx.x;   // 98304 total
    int kk = idx / GG;
    int g  = idx - kk * GG;
    float a = Whh[g * HH + 2*kk];
    float b = Whh[g * HH + 2*kk + 1];
    U32H2 c; c.h.x = (_Float16)a; c.h.y = (_Float16)b;
    Wt[idx] = c.u;
}

// Phase 0b: W_ih [768][128] f32 -> f16 (same layout)
__global__ void conv_wih(const float* __restrict__ Wih, _Float16* __restrict__ Wh){
    int idx = blockIdx.x * 256 + threadIdx.x;   // 98304 total
    Wh[idx] = (_Float16)Wih[idx];
}

// ---------------------------------------------------------------------------
// Phase 1: gi[bt][g] = sum_k x[bt][k]*W_ih[g][k] + b_ih[g]  via f16 MFMA.
// Block = 256 thr (4 waves). Each wave: M=16 rows, N=192 cols, K=128.
// ---------------------------------------------------------------------------
__global__ __launch_bounds__(256) void gi_mfma(const float* __restrict__ x,
                                               const _Float16* __restrict__ Wh,
                                               const float* __restrict__ bih,
                                               _Float16* __restrict__ gi){
    const int wave = threadIdx.x >> 6;
    const int lane = threadIdx.x & 63;
    const int l16  = lane & 15, q = lane >> 4;
    const int m    = blockIdx.x * 64 + wave * 16 + l16;   // bt row for A frag
    const int n0   = blockIdx.y * 192;                     // g col base
    f32x4 acc[12] = {};
    #pragma unroll
    for (int s = 0; s < 4; ++s){                           // K steps of 32
        const float* xp = x + (size_t)m * II + s*32 + q*8;
        float4 a0 = *(const float4*)xp;
        float4 a1 = *(const float4*)(xp + 4);
        half8 af = { (_Float16)a0.x,(_Float16)a0.y,(_Float16)a0.z,(_Float16)a0.w,
                     (_Float16)a1.x,(_Float16)a1.y,(_Float16)a1.z,(_Float16)a1.w };
        #pragma unroll
        for (int t = 0; t < 12; ++t){                      // N tiles of 16
            const _Float16* wp = Wh + (size_t)(n0 + t*16 + l16) * II + s*32 + q*8;
            half8 bf = *(const half8*)wp;
            acc[t] = __builtin_amdgcn_mfma_f32_16x16x32_f16(af, bf, acc[t], 0, 0, 0);
        }
    }
    // D layout: col = lane&15 (n), row = (lane>>4)*4 + reg (m)
    #pragma unroll
    for (int t = 0; t < 12; ++t){
        int n = n0 + t*16 + l16;
        float bv = bih[n];
        #pragma unroll
        for (int r = 0; r < 4; ++r){
            int row = blockIdx.x*64 + wave*16 + q*4 + r;
            gi[(size_t)row * GG + n] = (_Float16)(acc[t][r] + bv);
        }
    }
}

// ---------------------------------------------------------------------------
// Phase 2: recurrence. One block per batch element, 1024 threads (16 waves).
// DOT PHASE identical to the proven baseline: j = tid&255 (output col),
// q = tid>>8 (K-quarter, WAVE-UNIFORM -> broadcast LDS h reads).
// Changes vs baseline:
//   * partials combined via LDS atomicAdd into a TRIPLE-BUFFERED accumulator
//     (read at t, zeroed at t+1's gate phase, re-added at t+3 -> all windows
//     barrier-separated with ONE __syncthreads per step)
//   * gate phase all-wave redundant at jg = 64q+lane: each wave computes the
//     h-quarter it needs next step and writes a PER-WAVE hslot (same-wave
//     write->read: lgkmcnt only, no barrier)
// LESSON (r3): never make the h-read address lane-dependent (loses broadcast),
// never use __shfl (ds_bpermute = LDS-pipe traffic).
// ---------------------------------------------------------------------------
__global__ __launch_bounds__(1024, 4) void gru_rec(
        const unsigned int* __restrict__ Wt,   // [128][768] packed f16 pairs
        const _Float16* __restrict__ gi,       // [64][2048][768]
        const float* __restrict__ bhh,         // [768]
        float* __restrict__ hid)               // [64][2048][256]
{
    const int b    = blockIdx.x;
    const int tid  = threadIdx.x;
    const int j    = tid & 255;     // dot-phase output index
    const int q    = tid >> 8;      // K-quarter (wave-uniform)
    const int lane = tid & 63;
    const int w    = tid >> 6;      // wave id
    const int c    = w & 3;         // wave-in-group
    const int jg   = (q << 6) | lane;  // gate-phase hidden index (own quarter)

    unsigned int Wr[32], Wz[32], Wn[32];
    {
        const unsigned int* Wb = Wt + q * 32 * GG;
        #pragma unroll
        for (int m = 0; m < 32; ++m){
            Wr[m] = Wb[m * GG + j];
            Wz[m] = Wb[m * GG + j + 256];
            Wn[m] = Wb[m * GG + j + 512];
        }
    }
    const float br = bhh[jg], bz = bhh[jg + 256], bn = bhh[jg + 512];

    __shared__ float acc3[3][GG];                 // triple-buffered partial sums
    __shared__ __align__(16) _Float16 hslot[16][64];  // per-wave h quarter

    for (int i = tid; i < 3 * GG; i += 1024) ((float*)acc3)[i] = 0.f;
    hslot[w][lane] = (_Float16)0.f;               // 16*64 == 1024 exactly

    const _Float16* gib = gi + (size_t)b * TT * GG;
    float* hob = hid + (size_t)b * TT * HH;

    float h_prev = 0.f;
    float gr  = (float)gib[jg];
    float gz  = (float)gib[jg + 256];
    float gnv = (float)gib[jg + 512];

    const uint4* hvp = (const uint4*)hslot[w];    // wave-uniform broadcast base
    float* p0 = acc3[0];   // buffer for step t
    float* p1 = acc3[1];   // step t+1
    float* p2 = acc3[2];   // zero-target at step t (re-added at t+3)

    __syncthreads();

    for (int t = 0; t < TT; ++t){
        // prefetch next step's gi (coalesced, consumed next iteration)
        const int tn = (t + 1 < TT) ? t + 1 : t;
        const _Float16* gp = gib + (size_t)tn * GG;
        const _Float16 pr = gp[jg], pz = gp[jg + 256], pn = gp[jg + 512];

        // dot phase — identical to baseline (broadcast h reads)
        float ar = 0.f, az = 0.f, an = 0.f;
        #pragma unroll
        for (int mm = 0; mm < 8; ++mm){
            union { uint4 v; h2 p[4]; } hh;
            hh.v = hvp[mm];
            #pragma unroll
            for (int p = 0; p < 4; ++p){
                ar = fdot2f(Wr[4*mm + p], hh.p[p], ar);
                az = fdot2f(Wz[4*mm + p], hh.p[p], az);
                an = fdot2f(Wn[4*mm + p], hh.p[p], an);
            }
        }
        atomicAdd(&p0[j],       ar);
        atomicAdd(&p0[j + 256], az);
        atomicAdd(&p0[j + 512], an);
        __syncthreads();                           // the ONE barrier per step

        // gate phase — all waves, own-quarter jg
        const float sr = p0[jg], sz = p0[jg + 256], sn = p0[jg + 512];
        if (tid < GG) p2[tid] = 0.f;               // zero buf read at t-1

        float r = 1.f / (1.f + __expf(-(gr + br + sr)));
        float z = 1.f / (1.f + __expf(-(gz + bz + sz)));
        float tin = gnv + r * (sn + bn);
        tin = fminf(15.f, fmaxf(-15.f, tin));
        float e2 = __expf(2.f * tin);
        float n = (e2 - 1.f) / (e2 + 1.f);
        float hn = (1.f - z) * n + z * h_prev;
        h_prev = hn;

        hslot[w][lane] = (_Float16)hn;             // own-wave slot, no barrier
        if (c == q) hob[(size_t)t * HH + jg] = hn; // one wave per group stores

        gr = (float)pr; gz = (float)pz; gnv = (float)pn;

        float* tmp = p0; p0 = p1; p1 = p2; p2 = tmp;   // rotate buffers
    }
}

// ---------------------------------------------------------------------------
// Phase 3: outputs[bt] = dot(hiddens[bt], W_o) + b_o.  One wave per bt.
// ---------------------------------------------------------------------------
__global__ __launch_bounds__(256) void out_proj(const float* __restrict__ hid,
                                                const float* __restrict__ Wo,
                                                const float* __restrict__ bo,
                                                float* __restrict__ outp){
    const int w = threadIdx.x >> 6, l = threadIdx.x & 63;
    const size_t bt = (size_t)blockIdx.x * 4 + w;
    const float4 hv = ((const float4*)(hid + bt * HH))[l];
    const float4 wv = ((const float4*)Wo)[l];
    float s = hv.x*wv.x + hv.y*wv.y + hv.z*wv.z + hv.w*wv.w;
    #pragma unroll
    for (int off = 32; off > 0; off >>= 1) s += __shfl_down(s, off, 64);
    if (l == 0) outp[bt] = s + bo[0];
}

// ---------------------------------------------------------------------------
extern "C" void kernel_launch(void* const* d_in, const int* in_sizes, int n_in,
                              void* d_out, int out_size, void* d_ws, size_t ws_size,
                              hipStream_t stream) {
    const float* x   = (const float*)d_in[0];
    const float* Wih = (const float*)d_in[1];
    const float* Whh = (const float*)d_in[2];
    const float* bih = (const float*)d_in[3];
    const float* bhh = (const float*)d_in[4];
    const float* Wo  = (const float*)d_in[5];
    const float* bo  = (const float*)d_in[6];

    float* outputs = (float*)d_out;                      // [64][2048][1]
    float* hiddens = (float*)d_out + (size_t)BB * TT;    // [64][2048][256]

    // Workspace: Wt (393216 B) | Wih f16 (196608 B) | gi f16 (201326592 B)
    unsigned int* Wt = (unsigned int*)d_ws;
    _Float16* Wh = (_Float16*)((char*)d_ws + 128 * GG * sizeof(unsigned int));
    _Float16* gi = (_Float16*)((char*)Wh + (size_t)GG * II * sizeof(_Float16));

    conv_whh<<<dim3(98304 / 256), dim3(256), 0, stream>>>(Whh, Wt);
    conv_wih<<<dim3(98304 / 256), dim3(256), 0, stream>>>(Wih, Wh);
    gi_mfma <<<dim3((BB * TT) / 64, GG / 192), dim3(256), 0, stream>>>(x, Wh, bih, gi);
    gru_rec <<<dim3(BB), dim3(1024), 0, stream>>>(Wt, gi, bhh, hiddens);
    out_proj<<<dim3((BB * TT) / 4), dim3(256), 0, stream>>>(hiddens, Wo, bo, outputs);
}

// Round 5
// 5422.694 us; speedup vs baseline: 1.9272x; 1.9272x over previous
//
#include <hip/hip_runtime.h>
#include <hip/hip_bf16.h>

#define BB 64
#define TT 2048
#define II 128
#define HH 256
#define GG 768   // 3*H

typedef _Float16 h2 __attribute__((ext_vector_type(2)));
typedef _Float16 half8 __attribute__((ext_vector_type(8)));
typedef float f32x4 __attribute__((ext_vector_type(4)));
union U32H2 { unsigned int u; h2 h; };

static __device__ __forceinline__ float fdot2f(unsigned int w, h2 hv, float acc){
#if __has_builtin(__builtin_amdgcn_fdot2)
    U32H2 c; c.u = w;
    return __builtin_amdgcn_fdot2(c.h, hv, acc, false);
#else
    U32H2 c; c.u = w;
    return acc + (float)c.h.x * (float)hv.x + (float)c.h.y * (float)hv.y;
#endif
}

// ---------------------------------------------------------------------------
// Phase 0a: W_hh [768][256] f32 -> packed f16 pairs, transposed:
// Wt[kk][g] = pack(W_hh[g][2kk], W_hh[g][2kk+1]), kk in [0,128), g in [0,768)
// ---------------------------------------------------------------------------
__global__ void conv_whh(const float* __restrict__ Whh, unsigned int* __restrict__ Wt){
    int idx = blockIdx.x * 256 + threadIdx.x;   // 98304 total
    int kk = idx / GG;
    int g  = idx - kk * GG;
    float a = Whh[g * HH + 2*kk];
    float b = Whh[g * HH + 2*kk + 1];
    U32H2 c; c.h.x = (_Float16)a; c.h.y = (_Float16)b;
    Wt[idx] = c.u;
}

// Phase 0b: W_ih [768][128] f32 -> f16 (same layout)
__global__ void conv_wih(const float* __restrict__ Wih, _Float16* __restrict__ Wh){
    int idx = blockIdx.x * 256 + threadIdx.x;   // 98304 total
    Wh[idx] = (_Float16)Wih[idx];
}

// ---------------------------------------------------------------------------
// Phase 1: gi[bt][g] = sum_k x[bt][k]*W_ih[g][k] + b_ih[g]  via f16 MFMA.
// Block = 256 thr (4 waves). Each wave: M=16 rows, N=192 cols, K=128.
// ---------------------------------------------------------------------------
__global__ __launch_bounds__(256) void gi_mfma(const float* __restrict__ x,
                                               const _Float16* __restrict__ Wh,
                                               const float* __restrict__ bih,
                                               _Float16* __restrict__ gi){
    const int wave = threadIdx.x >> 6;
    const int lane = threadIdx.x & 63;
    const int l16  = lane & 15, q = lane >> 4;
    const int m    = blockIdx.x * 64 + wave * 16 + l16;   // bt row for A frag
    const int n0   = blockIdx.y * 192;                     // g col base
    f32x4 acc[12] = {};
    #pragma unroll
    for (int s = 0; s < 4; ++s){                           // K steps of 32
        const float* xp = x + (size_t)m * II + s*32 + q*8;
        float4 a0 = *(const float4*)xp;
        float4 a1 = *(const float4*)(xp + 4);
        half8 af = { (_Float16)a0.x,(_Float16)a0.y,(_Float16)a0.z,(_Float16)a0.w,
                     (_Float16)a1.x,(_Float16)a1.y,(_Float16)a1.z,(_Float16)a1.w };
        #pragma unroll
        for (int t = 0; t < 12; ++t){                      // N tiles of 16
            const _Float16* wp = Wh + (size_t)(n0 + t*16 + l16) * II + s*32 + q*8;
            half8 bf = *(const half8*)wp;
            acc[t] = __builtin_amdgcn_mfma_f32_16x16x32_f16(af, bf, acc[t], 0, 0, 0);
        }
    }
    // D layout: col = lane&15 (n), row = (lane>>4)*4 + reg (m)
    #pragma unroll
    for (int t = 0; t < 12; ++t){
        int n = n0 + t*16 + l16;
        float bv = bih[n];
        #pragma unroll
        for (int r = 0; r < 4; ++r){
            int row = blockIdx.x*64 + wave*16 + q*4 + r;
            gi[(size_t)row * GG + n] = (_Float16)(acc[t][r] + bv);
        }
    }
}

// ---------------------------------------------------------------------------
// Phase 2: recurrence — NO K-SPLIT. One block per batch, 256 threads (4 waves,
// 1 wave/SIMD). Thread j owns output j with the FULL K=256 dot for all 3
// gates: 384 packed f16-pair weight VGPRs (budget 512 at occupancy 1 via
// __launch_bounds__(256,1); no spill expected below ~450 per m08).
// Consequences: ZERO partial exchange, ZERO serial phase, ONE barrier/step.
// h double-buffered in LDS (1 KB), reads wave-uniform -> broadcast.
// LESSONS: r2: don't stage LDS reads into arrays (spill); r3: never per-lane
// h addresses, no __shfl; r4: never LDS atomics.
// ---------------------------------------------------------------------------
__global__ __launch_bounds__(256, 1) void gru_rec(
        const unsigned int* __restrict__ Wt,   // [128][768] packed f16 pairs
        const _Float16* __restrict__ gi,       // [64][2048][768]
        const float* __restrict__ bhh,         // [768]
        float* __restrict__ hid)               // [64][2048][256]
{
    const int b = blockIdx.x;
    const int j = threadIdx.x;                 // 0..255: owned hidden index

    unsigned int Wr[128], Wz[128], Wn[128];
    #pragma unroll
    for (int m = 0; m < 128; ++m){
        Wr[m] = Wt[m * GG + j];
        Wz[m] = Wt[m * GG + j + 256];
        Wn[m] = Wt[m * GG + j + 512];
    }
    const float br = bhh[j], bz = bhh[j + 256], bn = bhh[j + 512];

    __shared__ __align__(16) _Float16 hbuf[2][HH];   // double-buffered h (f16)
    hbuf[0][j] = (_Float16)0.f;
    hbuf[1][j] = (_Float16)0.f;

    const _Float16* gib = gi + (size_t)b * TT * GG;
    float* hob = hid + (size_t)b * TT * HH;

    float h_prev = 0.f;
    float gr  = (float)gib[j];
    float gz  = (float)gib[j + 256];
    float gnv = (float)gib[j + 512];

    __syncthreads();

    for (int t = 0; t < TT; ++t){
        // prefetch next step's gi (coalesced; hidden under the dot phase)
        const int tn = (t + 1 < TT) ? t + 1 : t;
        const _Float16* gp = gib + (size_t)tn * GG;
        const _Float16 pr = gp[j], pz = gp[j + 256], pn = gp[j + 512];

        // full-K dot: 32 broadcast uint4 LDS reads, consumed immediately;
        // 3 independent fdot2 chains saturate issue at 1 wave/SIMD.
        const uint4* hv = (const uint4*)hbuf[t & 1];
        float ar = 0.f, az = 0.f, an = 0.f;
        #pragma unroll
        for (int mm = 0; mm < 32; ++mm){
            union { uint4 v; h2 p[4]; } hh;
            hh.v = hv[mm];
            #pragma unroll
            for (int p = 0; p < 4; ++p){
                ar = fdot2f(Wr[4*mm + p], hh.p[p], ar);
                az = fdot2f(Wz[4*mm + p], hh.p[p], az);
                an = fdot2f(Wn[4*mm + p], hh.p[p], an);
            }
        }

        // gate math — fully parallel, every thread its own j
        float r = 1.f / (1.f + __expf(-(gr + br + ar)));
        float z = 1.f / (1.f + __expf(-(gz + bz + az)));
        float tin = gnv + r * (an + bn);
        tin = fminf(15.f, fmaxf(-15.f, tin));
        float e2 = __expf(2.f * tin);
        float n = (e2 - 1.f) / (e2 + 1.f);
        float hn = (1.f - z) * n + z * h_prev;
        h_prev = hn;

        hbuf[(t + 1) & 1][j] = (_Float16)hn;
        hob[(size_t)t * HH + j] = hn;          // coalesced f32 store

        gr = (float)pr; gz = (float)pz; gnv = (float)pn;
        __syncthreads();                        // the ONE barrier per step
    }
}

// ---------------------------------------------------------------------------
// Phase 3: outputs[bt] = dot(hiddens[bt], W_o) + b_o.  One wave per bt.
// ---------------------------------------------------------------------------
__global__ __launch_bounds__(256) void out_proj(const float* __restrict__ hid,
                                                const float* __restrict__ Wo,
                                                const float* __restrict__ bo,
                                                float* __restrict__ outp){
    const int w = threadIdx.x >> 6, l = threadIdx.x & 63;
    const size_t bt = (size_t)blockIdx.x * 4 + w;
    const float4 hv = ((const float4*)(hid + bt * HH))[l];
    const float4 wv = ((const float4*)Wo)[l];
    float s = hv.x*wv.x + hv.y*wv.y + hv.z*wv.z + hv.w*wv.w;
    #pragma unroll
    for (int off = 32; off > 0; off >>= 1) s += __shfl_down(s, off, 64);
    if (l == 0) outp[bt] = s + bo[0];
}

// ---------------------------------------------------------------------------
extern "C" void kernel_launch(void* const* d_in, const int* in_sizes, int n_in,
                              void* d_out, int out_size, void* d_ws, size_t ws_size,
                              hipStream_t stream) {
    const float* x   = (const float*)d_in[0];
    const float* Wih = (const float*)d_in[1];
    const float* Whh = (const float*)d_in[2];
    const float* bih = (const float*)d_in[3];
    const float* bhh = (const float*)d_in[4];
    const float* Wo  = (const float*)d_in[5];
    const float* bo  = (const float*)d_in[6];

    float* outputs = (float*)d_out;                      // [64][2048][1]
    float* hiddens = (float*)d_out + (size_t)BB * TT;    // [64][2048][256]

    // Workspace: Wt (393216 B) | Wih f16 (196608 B) | gi f16 (201326592 B)
    unsigned int* Wt = (unsigned int*)d_ws;
    _Float16* Wh = (_Float16*)((char*)d_ws + 128 * GG * sizeof(unsigned int));
    _Float16* gi = (_Float16*)((char*)Wh + (size_t)GG * II * sizeof(_Float16));

    conv_whh<<<dim3(98304 / 256), dim3(256), 0, stream>>>(Whh, Wt);
    conv_wih<<<dim3(98304 / 256), dim3(256), 0, stream>>>(Wih, Wh);
    gi_mfma <<<dim3((BB * TT) / 64, GG / 192), dim3(256), 0, stream>>>(x, Wh, bih, gi);
    gru_rec <<<dim3(BB), dim3(256), 0, stream>>>(Wt, gi, bhh, hiddens);
    out_proj<<<dim3((BB * TT) / 4), dim3(256), 0, stream>>>(hiddens, Wo, bo, outputs);
}